// Round 8
// baseline (821.174 us; speedup 1.0000x reference)
//
#include <hip/hip_runtime.h>
#include <hip/hip_bf16.h>

// QuantizedLinear: out[m,o] = sum_k x[m,k] * (q[o,k]-z[o,g])*s[o,g] + b[o]
// M=8192, K=4096, N=11008. Pass1: dequant W->bf16 (row-major B^T), cvt x->bf16.
// Pass2: 256x256 bf16 GEMM, BK=32, QUAD-buffered LDS (4 x 32KB), ONE barrier
// per K-tile, counted vmcnt(8) (stages of t+2,t+3 stay in flight - T4).
// At BK=32 a 16x32 fragment is a contiguous 1KB row-run in LDS -> ds_read_b128
// is bijective over 1KB (intrinsic-minimum banking, NO swizzle needed) and
// global_load_lds's linear dest matches the layout exactly.
// Stage schedule: tile t stages tile t+3 into buf[(t+3)&3]; buf[(t+3)&3]'s old
// readers finished at barrier(t-1) < any tile-t instruction. vmcnt(8) at
// barrier(t) drains exactly t+1's 4 loads (8 = t+2,t+3 in flight).
// T1 XCD swizzle, T5 setprio.

#define K_DIM 4096
#define N_DIM 11008
#define M_DIM 8192
#define NGRP 32

typedef __bf16 bf16x8 __attribute__((ext_vector_type(8)));
typedef float f32x4 __attribute__((ext_vector_type(4)));
typedef unsigned short u16x8 __attribute__((ext_vector_type(8)));

__device__ __forceinline__ unsigned short f2bf(float f) {
  unsigned u = __builtin_bit_cast(unsigned, f);
  return (unsigned short)((u + 0x7FFFu + ((u >> 16) & 1u)) >> 16);  // RNE
}

__device__ __forceinline__ void gload_lds16(const void* g, void* l) {
  __builtin_amdgcn_global_load_lds(
      (const __attribute__((address_space(1))) unsigned int*)(unsigned long long)g,
      (__attribute__((address_space(3))) unsigned int*)(unsigned int)(unsigned long long)l,
      16, 0, 0);
}

// ---- pass 1a: x fp32 -> bf16 ----
__global__ __launch_bounds__(256) void cvt_x_kernel(const float4* __restrict__ x4,
                                                    u16x8* __restrict__ xb) {
  int i = blockIdx.x * 256 + threadIdx.x;
  float4 a = x4[2 * i], b = x4[2 * i + 1];
  u16x8 r;
  r[0] = f2bf(a.x); r[1] = f2bf(a.y); r[2] = f2bf(a.z); r[3] = f2bf(a.w);
  r[4] = f2bf(b.x); r[5] = f2bf(b.y); r[6] = f2bf(b.z); r[7] = f2bf(b.w);
  xb[i] = r;
}

// ---- pass 1b: dequant W -> bf16 (row-major [N][K]) ----
__global__ __launch_bounds__(256) void dequant_kernel(const int4* __restrict__ q4,
                                                      const float* __restrict__ scales,
                                                      const float* __restrict__ zeros,
                                                      u16x8* __restrict__ wb) {
  int t = blockIdx.x * 256 + threadIdx.x;
  int o = t >> 9;
  int j8 = t & 511;
  int g = j8 >> 4;
  float s = scales[o * NGRP + g];
  float z = zeros[o * NGRP + g];
  float nzs = -z * s;
  int4 qa = q4[2 * t], qb = q4[2 * t + 1];
  u16x8 r;
  r[0] = f2bf(fmaf((float)qa.x, s, nzs));
  r[1] = f2bf(fmaf((float)qa.y, s, nzs));
  r[2] = f2bf(fmaf((float)qa.z, s, nzs));
  r[3] = f2bf(fmaf((float)qa.w, s, nzs));
  r[4] = f2bf(fmaf((float)qb.x, s, nzs));
  r[5] = f2bf(fmaf((float)qb.y, s, nzs));
  r[6] = f2bf(fmaf((float)qb.z, s, nzs));
  r[7] = f2bf(fmaf((float)qb.w, s, nzs));
  wb[t] = r;
}

// ---- pass 2: 256x256 bf16 GEMM, BK=32, quad-buffer, 1 barrier/tile ----
#define BAR() __builtin_amdgcn_s_barrier()
#define SCHED0() __builtin_amdgcn_sched_barrier(0)

__global__ __launch_bounds__(512, 2) void gemm_kernel(const unsigned short* __restrict__ A,
                                                      const unsigned short* __restrict__ B,
                                                      const float* __restrict__ bias,
                                                      float* __restrict__ C) {
  extern __shared__ unsigned short smem[];
  // sA[buf b] = smem + b*8192 elems (16KB: 256 rows x 32 k)
  // sB[buf b] = smem + 32768 + b*8192

  const int bid = blockIdx.x;
  // T1: 1376 blocks, 1376 % 8 == 0 -> simple bijective XCD swizzle.
  const int swz = (bid & 7) * 172 + (bid >> 3);
  const int tm = swz / 43, tn = swz % 43;

  const int tid = threadIdx.x;
  const int w = tid >> 6, l = tid & 63;
  const int wr = w >> 2, wc = w & 3;

  // staging: thread t covers row t>>2, 8-elem slot t&3; 2 instrs cover 256 rows.
  const int dsto = tid * 8;  // LDS elem offset == (row)*32 + slot*8, linear in tid
  const unsigned short* gA = A + (size_t)(tm * 256 + (tid >> 2)) * K_DIM + (tid & 3) * 8;
  const unsigned short* gB = B + (size_t)(tn * 256 + (tid >> 2)) * K_DIM + (tid & 3) * 8;

#define STG(tt, bufi)                                                            \
  do {                                                                           \
    const unsigned short* _sa = gA + (size_t)(tt) * 32;                          \
    const unsigned short* _sb = gB + (size_t)(tt) * 32;                          \
    unsigned short* _da = smem + (bufi) * 8192 + dsto;                           \
    unsigned short* _db = smem + 32768 + (bufi) * 8192 + dsto;                   \
    gload_lds16(_sa, _da);                                                       \
    gload_lds16(_sa + (size_t)128 * K_DIM, _da + 4096);                          \
    gload_lds16(_sb, _db);                                                       \
    gload_lds16(_sb + (size_t)128 * K_DIM, _db + 4096);                          \
  } while (0)

  // fragment read coords: lane row-in-16 = l&15, k-slot = l>>4
  const int fr = l & 15, sb = l >> 4;
  const int abase = wr * 4096 + fr * 32 + sb * 8;  // + m*512 per 16-row frag
  const int bbase = wc * 2048 + fr * 32 + sb * 8;  // + n*512

  bf16x8 av[8], bv[4];
  f32x4 acc[8][4] = {};

#define TILE_BODY(cbuf)                                                          \
  {                                                                              \
    const unsigned short* _ca = smem + (cbuf) * 8192;                            \
    const unsigned short* _cb = smem + 32768 + (cbuf) * 8192;                    \
    _Pragma("unroll") for (int m = 0; m < 8; ++m)                                \
        av[m] = *(const bf16x8*)(_ca + abase + m * 512);                         \
    _Pragma("unroll") for (int n = 0; n < 4; ++n)                                \
        bv[n] = *(const bf16x8*)(_cb + bbase + n * 512);                         \
    __builtin_amdgcn_s_setprio(1);                                               \
    _Pragma("unroll") for (int m = 0; m < 8; ++m)                                \
    _Pragma("unroll") for (int n = 0; n < 4; ++n)                                \
        acc[m][n] = __builtin_amdgcn_mfma_f32_16x16x32_bf16(av[m], bv[n],        \
                                                            acc[m][n], 0, 0, 0); \
    __builtin_amdgcn_s_setprio(0);                                               \
  }

#define TILE(tt, cbuf, nbuf, VMN)                                                \
  {                                                                              \
    STG(tt + 3, nbuf);                                                           \
    TILE_BODY(cbuf);                                                             \
    SCHED0();                                                                    \
    asm volatile("s_waitcnt vmcnt(" VMN ")" ::: "memory");                       \
    BAR();                                                                       \
    SCHED0();                                                                    \
  }

  // ---- prologue: stage tiles 0,1,2 ----
  STG(0, 0);
  STG(1, 1);
  STG(2, 2);
  SCHED0();
  asm volatile("s_waitcnt vmcnt(8)" ::: "memory");  // tile 0 resident
  BAR();
  SCHED0();

  // ---- main: tiles 0..123 (stage through 126), 31 x 4-tile chunks ----
  for (int t4 = 0; t4 < 124; t4 += 4) {
    TILE(t4 + 0, 0, 3, "8");
    TILE(t4 + 1, 1, 0, "8");
    TILE(t4 + 2, 2, 1, "8");
    TILE(t4 + 3, 3, 2, "8");
  }

  // ---- peel tiles 124..127 ----
  // t=124: stage 127 -> buf3; outstanding after issue = {125,126,127} = 12
  STG(127, 3);
  TILE_BODY(0);
  SCHED0();
  asm volatile("s_waitcnt vmcnt(8)" ::: "memory");  // 125 resident
  BAR();
  SCHED0();
  // t=125: outstanding {126,127} = 8
  TILE_BODY(1);
  SCHED0();
  asm volatile("s_waitcnt vmcnt(4)" ::: "memory");  // 126 resident
  BAR();
  SCHED0();
  // t=126
  TILE_BODY(2);
  SCHED0();
  asm volatile("s_waitcnt vmcnt(0)" ::: "memory");  // 127 resident
  BAR();
  SCHED0();
  // t=127: compute only
  TILE_BODY(3);

  // ---- epilogue: C/D layout col=lane&15, row=(lane>>4)*4+reg ----
  const int r0 = tm * 256 + wr * 128 + sb * 4;
  const int c0 = tn * 256 + wc * 64 + fr;
#pragma unroll
  for (int n = 0; n < 4; ++n) {
    const int col = c0 + n * 16;
    const float bvl = bias[col];
#pragma unroll
    for (int m = 0; m < 8; ++m) {
      const int row = r0 + m * 16;
#pragma unroll
      for (int jj = 0; jj < 4; ++jj)
        C[(size_t)(row + jj) * N_DIM + col] = acc[m][n][jj] + bvl;
    }
  }
}

extern "C" void kernel_launch(void* const* d_in, const int* in_sizes, int n_in,
                              void* d_out, int out_size, void* d_ws, size_t ws_size,
                              hipStream_t stream) {
  const float* x = (const float*)d_in[0];
  const int* qw = (const int*)d_in[1];
  const float* sc = (const float*)d_in[2];
  const float* zr = (const float*)d_in[3];
  const float* bs = (const float*)d_in[4];
  float* out = (float*)d_out;

  const size_t xb_bytes = (size_t)M_DIM * K_DIM * 2;
  const size_t wb_bytes = (size_t)N_DIM * K_DIM * 2;
  if (ws_size < xb_bytes + wb_bytes) return;

  unsigned short* xb = (unsigned short*)d_ws;
  unsigned short* wb = (unsigned short*)((char*)d_ws + xb_bytes);

  (void)hipFuncSetAttribute((const void*)gemm_kernel,
                            hipFuncAttributeMaxDynamicSharedMemorySize, 131072);

  cvt_x_kernel<<<(M_DIM * K_DIM / 8) / 256, 256, 0, stream>>>((const float4*)x, (u16x8*)xb);
  dequant_kernel<<<(N_DIM * K_DIM / 8) / 256, 256, 0, stream>>>((const int4*)qw, sc, zr,
                                                                (u16x8*)wb);
  gemm_kernel<<<(M_DIM / 256) * (N_DIM / 256), 512, 131072, stream>>>(xb, wb, bs, out);
}